// Round 18
// baseline (48.362 us; speedup 1.0000x reference)
//
#include <hip/hip_runtime.h>
#include <hip/hip_bf16.h>

#define BN 4096
#define DD 128

// All five bf16 matrices are pre-scaled by SQS = sqrt(2*log2(e)), so the
// MFMA dot product is directly the exp2 argument: 2^(SQS^2 * dot) = e^(2*dot).
#define SQS 1.69864356f

typedef __bf16 bf16x8 __attribute__((ext_vector_type(8)));
typedef float f32x16 __attribute__((ext_vector_type(16)));
typedef float f32x2  __attribute__((ext_vector_type(2)));

// RAW v_exp_f32 (quarter-rate trans pipe, 1 instruction).  Plain
// __builtin_exp2f without fast-math expands to a guarded multi-instruction
// sequence (~5 extra VALU/exp x 100.7M exps -- the r16(54% VALUBusy) vs
// r17 delta, worth ~8us).  Inputs bounded (|arg| < 16) -> raw is safe.
__device__ __forceinline__ float fast_exp2(float x) {
#if __has_builtin(__builtin_amdgcn_exp2f)
    return __builtin_amdgcn_exp2f(x);
#else
    float r;
    asm("v_exp_f32 %0, %1" : "=v"(r) : "v"(x));
    return r;
#endif
}

// ---------------- prep: f32 -> bf16 fragment-major (+gather), diag dots -----
// Fragment-major: per 32-row panel (8192 B), granule g = s*64 + h*32 + r
// holds row r, elements [16s+8h, 16s+8h+8).
__global__ __launch_bounds__(256) void prep_kernel(
    const float* __restrict__ z1, const float* __restrict__ z2,
    const float* __restrict__ attr, const int* __restrict__ uni,
    char* __restrict__ Z1f, char* __restrict__ Z2f,
    char* __restrict__ G1f, char* __restrict__ G2f, char* __restrict__ Af,
    float* __restrict__ d1, float* __restrict__ d2, float* __restrict__ d3,
    float* __restrict__ S1, float* __restrict__ S2, float* __restrict__ out)
{
    int p = blockIdx.x;        // half-panel 0..255 (16 rows each)
    int t = threadIdx.x;       // 0..255
    int gid = p * 256 + t;
    if (gid < 4 * BN) { S1[gid] = 0.f; S2[gid] = 0.f; }
    if (gid == 0) out[0] = 0.f;

    int r = t >> 4, q = t & 15;        // row-in-block (16), col-eighth (8 f32)
    int grow = p * 16 + r;
    int arow = uni[grow];

    __shared__ __hip_bfloat16 lp[5][16][128];

    const float* sp[5] = { z1 + (size_t)grow * DD, z2 + (size_t)grow * DD,
                           z1 + (size_t)arow * DD, z2 + (size_t)arow * DD,
                           attr + (size_t)arow * DD };
    float v[5][8];
    #pragma unroll
    for (int m = 0; m < 5; m++) {
        const float4* s4 = (const float4*)(sp[m] + q * 8);
        #pragma unroll
        for (int i = 0; i < 2; i++) {
            float4 f = s4[i];
            v[m][4*i+0] = f.x; v[m][4*i+1] = f.y;
            v[m][4*i+2] = f.z; v[m][4*i+3] = f.w;
        }
    }
    float p1 = 0.f, p2 = 0.f, p3 = 0.f;
    #pragma unroll
    for (int e = 0; e < 8; e++) {
        p3 += v[0][e] * v[1][e];
        p1 += v[2][e] * v[4][e];
        p2 += v[3][e] * v[4][e];
    }
    #pragma unroll
    for (int m = 1; m < 16; m <<= 1) {
        p1 += __shfl_xor(p1, m);
        p2 += __shfl_xor(p2, m);
        p3 += __shfl_xor(p3, m);
    }
    if (q == 0) { d1[grow] = p1; d2[grow] = p2; d3[grow] = p3; }

    #pragma unroll
    for (int m = 0; m < 5; m++)
        #pragma unroll
        for (int e = 0; e < 8; e++)
            lp[m][r][q * 8 + e] = __float2bfloat16(v[m][e] * SQS);
    __syncthreads();

    int panel = p >> 1, lo = (p & 1) * 16;
    char* dsts[5] = { Z1f, Z2f, G1f, G2f, Af };
    int s = t >> 5, h = (t >> 4) & 1, rl = t & 15;   // granule coords
    int g = s * 64 + h * 32 + lo + rl;
    #pragma unroll
    for (int m = 0; m < 5; m++) {
        bf16x8 val = *reinterpret_cast<const bf16x8*>(&lp[m][rl][s * 16 + h * 8]);
        *reinterpret_cast<bf16x8*>(dsts[m] + (size_t)panel * 8192 + (size_t)g * 16) = val;
    }
}

// ---------------- sweep: free-running waves, global->reg Y stream -----------
// 4096 waves (1024 x 4-wave blocks) = EXACTLY 16 waves/CU (the 4/SIMD max at
// VGPR ~104) -- up from r17's 12/CU; the extra TLP fills MFMA/trans/L2
// latency.  Each wave owns 64 X-rows (xb0/xb1 in regs) and streams its
// Y-chunk (jobs 0/1: 256 rows; jobs 2/3: 512 rows) straight from global
// (L2-resident) into NAMED ping-pong register buffers yA/yB.
// ZERO LDS / ZERO barriers / ZERO DS-pipe.  Swapped MFMA operands (A=Y,B=X):
// Y-rowsum happens inside the accumulate; 4 atomicAdds/lane at the end.
// e/e^2 accumulate into float2 pairs -> v_pk_add/v_pk_fma (halves acc VALU).
// Spill discipline: loop ROLLED, static buffer names (rule #20), no VGPR cap.
__global__ __launch_bounds__(256) void sweep_kernel(
    const char* __restrict__ Z1f, const char* __restrict__ Z2f,
    const char* __restrict__ G1f, const char* __restrict__ G2f,
    const char* __restrict__ Af,
    float* __restrict__ S1, float* __restrict__ S2)
{
    int gwid = blockIdx.x * 4 + (threadIdx.x >> 6);   // 0..4095
    int lane = threadIdx.x & 63;
    int r = lane & 31, h = lane >> 5;

    int job, xblk, npairs;
    const char *X, *Y;
    size_t yoff;
    if (gwid < 2048) {            // jobs 0/1: X=G1f/G2f vs Y=Af, 16 x 256-row
        job = gwid >> 10;
        int rem = gwid & 1023;
        xblk = rem >> 4;          // 0..63
        int yc = rem & 15;        // 0..15
        X = job ? G2f : G1f;
        Y = Af;
        yoff = (size_t)yc * 65536;    // 256 rows
        npairs = 4;                   // 8 panels
    } else {                      // jobs 2/3: X=Z1f/Z2f vs Y=concat(Z1,Z2)
        int g2 = gwid - 2048;
        job = 2 + (g2 >> 10);
        int rem = g2 & 1023;
        xblk = rem >> 4;          // 0..63
        int yc = rem & 15;        // 0..15
        X = (job == 2) ? Z1f : Z2f;
        Y = (yc < 8) ? Z1f : Z2f;
        yoff = (size_t)(yc & 7) * 131072;  // 512 rows
        npairs = 8;                   // 16 panels
    }

    size_t laneoff = (size_t)(h * 512 + r * 16);

    // X: two 32-row panels (B operand), held in registers for the whole sweep.
    const char* xp = X + (size_t)(xblk * 2) * 8192 + laneoff;
    bf16x8 xb0[8], xb1[8];
    #pragma unroll
    for (int s = 0; s < 8; s++) {
        xb0[s] = *reinterpret_cast<const bf16x8*>(xp + s * 1024);
        xb1[s] = *reinterpret_cast<const bf16x8*>(xp + 8192 + s * 1024);
    }

    f32x2 s0a = {0.f, 0.f}, s0b = {0.f, 0.f};   // X-group 0: sum e, sum e^2
    f32x2 s1a = {0.f, 0.f}, s1b = {0.f, 0.f};   // X-group 1

    bf16x8 yA[8], yB[8];
    const char* ybase = Y + yoff + laneoff;

    // panel 0 -> yA
    #pragma unroll
    for (int s = 0; s < 8; s++)
        yA[s] = *reinterpret_cast<const bf16x8*>(ybase + s * 1024);

#define COMPY(BUF)                                                           \
    {                                                                        \
        f32x16 c0, c1;                                                       \
        _Pragma("unroll")                                                    \
        for (int q = 0; q < 16; q++) { c0[q] = 0.f; c1[q] = 0.f; }           \
        _Pragma("unroll")                                                    \
        for (int s = 0; s < 8; s++) {                                        \
            c0 = __builtin_amdgcn_mfma_f32_32x32x16_bf16(BUF[s], xb0[s], c0, 0, 0, 0); \
            c1 = __builtin_amdgcn_mfma_f32_32x32x16_bf16(BUF[s], xb1[s], c1, 0, 0, 0); \
        }                                                                    \
        _Pragma("unroll")                                                    \
        for (int q = 0; q < 8; q++) {                                        \
            f32x2 e0 = { fast_exp2(c0[2*q]), fast_exp2(c0[2*q+1]) };         \
            s0a += e0;                                                       \
            s0b = __builtin_elementwise_fma(e0, e0, s0b);                    \
            f32x2 e1 = { fast_exp2(c1[2*q]), fast_exp2(c1[2*q+1]) };         \
            s1a += e1;                                                       \
            s1b = __builtin_elementwise_fma(e1, e1, s1b);                    \
        }                                                                    \
    }

    #pragma clang loop unroll(disable)
    for (int it = 0; it < npairs; it++) {
        // prefetch odd panel -> yB
        #pragma unroll
        for (int s = 0; s < 8; s++)
            yB[s] = *reinterpret_cast<const bf16x8*>(ybase + 8192 + s * 1024);
        COMPY(yA)                          // compute even panel
        if (it < npairs - 1) {             // prefetch next even panel -> yA
            #pragma unroll
            for (int s = 0; s < 8; s++)
                yA[s] = *reinterpret_cast<const bf16x8*>(ybase + 16384 + s * 1024);
        }
        COMPY(yB)                          // compute odd panel
        ybase += 16384;
    }
#undef COMPY

    // Each lane holds partials (its h-half of every panel's Y-rows) for X-row
    // xblk*64 + xg*32 + r; both h lanes atomicAdd disjoint Y contributions.
    {
        int row0 = xblk * 64 + r;
        int row1 = xblk * 64 + 32 + r;
        atomicAdd(&S1[job * BN + row0], s0a.x + s0a.y);
        atomicAdd(&S2[job * BN + row0], s0b.x + s0b.y);
        atomicAdd(&S1[job * BN + row1], s1a.x + s1a.y);
        atomicAdd(&S2[job * BN + row1], s1b.x + s1b.y);
    }
}

// ---------------- finalize: per-row loss terms -> weighted mean --------------
__global__ __launch_bounds__(256) void finalize_kernel(
    const float* __restrict__ S1, const float* __restrict__ S2,
    const float* __restrict__ d1, const float* __restrict__ d2,
    const float* __restrict__ d3, float* __restrict__ out)
{
    int idx = blockIdx.x * 256 + threadIdx.x;   // 0..16383
    float term = 0.f;
    const float EM2 = 0.13533528323661270f;     // e^-2
    if (idx < 8192) {                           // inter jobs 0/1
        int j = idx >> 12, i = idx & 4095;
        float dv = j ? d2[i] : d1[i];
        float n = 4095.f;
        float pos = __expf(2.f * dv);
        float s1 = S1[j * BN + i] - pos;
        float s2 = S2[j * BN + i] - pos * pos;
        float rw = s2 * n / s1;
        float ng = (-0.1f * n * pos + rw) * (1.f / 0.9f);
        ng = fmaxf(ng, n * EM2);
        term = logf((pos + ng) / pos) * (0.5f / 4096.f);
    } else {                                    // intra rows 0..8191
        int i = idx - 8192;
        int ii = i & 4095;
        int job = 2 + (i >> 12);
        float n = 8190.f;
        const float E2 = 7.3890560989306495f, E4 = 54.598150033144236f;
        float pos = __expf(2.f * d3[ii]);
        float s1 = S1[job * BN + ii] - E2 - pos;
        float s2 = S2[job * BN + ii] - E4 - pos * pos;
        float rw = s2 * n / s1;
        float ng = (-0.1f * n * pos + rw) * (1.f / 0.9f);
        ng = fmaxf(ng, n * EM2);
        term = logf((pos + ng) / pos) * (1.f / 8192.f);
    }

    #pragma unroll
    for (int m = 1; m < 64; m <<= 1) term += __shfl_xor(term, m);
    __shared__ float sm[4];
    int wid = threadIdx.x >> 6;
    if ((threadIdx.x & 63) == 0) sm[wid] = term;
    __syncthreads();
    if (threadIdx.x == 0) atomicAdd(out, sm[0] + sm[1] + sm[2] + sm[3]);
}

extern "C" void kernel_launch(void* const* d_in, const int* in_sizes, int n_in,
                              void* d_out, int out_size, void* d_ws, size_t ws_size,
                              hipStream_t stream)
{
    const float* z1   = (const float*)d_in[0];
    const float* z2   = (const float*)d_in[1];
    // d_in[2] = text_z : unused by the reference
    const float* attr = (const float*)d_in[3];
    const int*   uni  = (const int*)d_in[4];
    float* out = (float*)d_out;

    char* ws = (char*)d_ws;
    size_t matb = (size_t)BN * DD * 2;               // bytes per bf16 matrix
    char* Z1f = ws;
    char* Z2f = Z1f + matb;
    char* G1f = Z2f + matb;
    char* G2f = G1f + matb;
    char* Af  = G2f + matb;
    float* S1 = (float*)(ws + 5 * matb);
    float* S2 = S1 + 4 * BN;
    float* d1 = S2 + 4 * BN;
    float* d2 = d1 + BN;
    float* d3 = d2 + BN;

    prep_kernel<<<256, 256, 0, stream>>>(z1, z2, attr, uni,
                                         Z1f, Z2f, G1f, G2f, Af,
                                         d1, d2, d3, S1, S2, out);
    sweep_kernel<<<1024, 256, 0, stream>>>(Z1f, Z2f, G1f, G2f, Af, S1, S2);
    finalize_kernel<<<64, 256, 0, stream>>>(S1, S2, d1, d2, d3, out);
}

// Round 19
// 42.557 us; speedup vs baseline: 1.1364x; 1.1364x over previous
//
#include <hip/hip_runtime.h>
#include <hip/hip_bf16.h>

#define BN 4096
#define DD 128

// All five bf16 matrices are pre-scaled by SQS = sqrt(2*log2(e)), so the
// MFMA dot product is directly the exp2 argument: 2^(SQS^2 * dot) = e^(2*dot).
#define SQS 1.69864356f

typedef __bf16 bf16x8 __attribute__((ext_vector_type(8)));
typedef float f32x4 __attribute__((ext_vector_type(4)));

// RAW v_exp_f32 (quarter-rate trans pipe, 1 instruction; guarded builtin
// costs ~5 extra VALU/exp -- r16 vs r17 delta was ~8us).
__device__ __forceinline__ float fast_exp2(float x) {
#if __has_builtin(__builtin_amdgcn_exp2f)
    return __builtin_amdgcn_exp2f(x);
#else
    float r;
    asm("v_exp_f32 %0, %1" : "=v"(r) : "v"(x));
    return r;
#endif
}

// ---------------- prep: f32 -> bf16 fragment-major-16 (+gather), diag dots --
// 16x16x32 fragment layout: per 16-row panel (4096 B, 256 granules of 16 B),
// granule g holds row (g&15), elems [32*(g>>6) + 8*((g>>4)&3), +8).
// A lane l of slice s then reads granule s*64 + l at lane*16 + s*1024.
__global__ __launch_bounds__(256) void prep_kernel(
    const float* __restrict__ z1, const float* __restrict__ z2,
    const float* __restrict__ attr, const int* __restrict__ uni,
    char* __restrict__ Z1f, char* __restrict__ Z2f,
    char* __restrict__ G1f, char* __restrict__ G2f, char* __restrict__ Af,
    float* __restrict__ d1, float* __restrict__ d2, float* __restrict__ d3,
    float* __restrict__ S1, float* __restrict__ S2, float* __restrict__ out)
{
    int p = blockIdx.x;        // 16-row panel 0..255
    int t = threadIdx.x;       // 0..255
    int gid = p * 256 + t;
    if (gid < 4 * BN) { S1[gid] = 0.f; S2[gid] = 0.f; }
    if (gid == 0) out[0] = 0.f;

    int r = t >> 4, q = t & 15;        // row-in-panel (16), col-eighth (8 f32)
    int grow = p * 16 + r;
    int arow = uni[grow];

    __shared__ __hip_bfloat16 lp[5][16][128];

    const float* sp[5] = { z1 + (size_t)grow * DD, z2 + (size_t)grow * DD,
                           z1 + (size_t)arow * DD, z2 + (size_t)arow * DD,
                           attr + (size_t)arow * DD };
    float v[5][8];
    #pragma unroll
    for (int m = 0; m < 5; m++) {
        const float4* s4 = (const float4*)(sp[m] + q * 8);
        #pragma unroll
        for (int i = 0; i < 2; i++) {
            float4 f = s4[i];
            v[m][4*i+0] = f.x; v[m][4*i+1] = f.y;
            v[m][4*i+2] = f.z; v[m][4*i+3] = f.w;
        }
    }
    float p1 = 0.f, p2 = 0.f, p3 = 0.f;
    #pragma unroll
    for (int e = 0; e < 8; e++) {
        p3 += v[0][e] * v[1][e];
        p1 += v[2][e] * v[4][e];
        p2 += v[3][e] * v[4][e];
    }
    #pragma unroll
    for (int m = 1; m < 16; m <<= 1) {
        p1 += __shfl_xor(p1, m);
        p2 += __shfl_xor(p2, m);
        p3 += __shfl_xor(p3, m);
    }
    if (q == 0) { d1[grow] = p1; d2[grow] = p2; d3[grow] = p3; }

    #pragma unroll
    for (int m = 0; m < 5; m++)
        #pragma unroll
        for (int e = 0; e < 8; e++)
            lp[m][r][q * 8 + e] = __float2bfloat16(v[m][e] * SQS);
    __syncthreads();

    // Write phase: thread t writes granule t of panel p for each matrix.
    char* dsts[5] = { Z1f, Z2f, G1f, G2f, Af };
    int rw = t & 15;
    int ks = 32 * (t >> 6) + 8 * ((t >> 4) & 3);
    #pragma unroll
    for (int m = 0; m < 5; m++) {
        bf16x8 val = *reinterpret_cast<const bf16x8*>(&lp[m][rw][ks]);
        *reinterpret_cast<bf16x8*>(dsts[m] + (size_t)p * 4096 + (size_t)t * 16) = val;
    }
}

// ---------------- sweep: free-running waves, 16x16x32, small footprint -----
// 3072 waves (768 x 4-wave blocks), EQUAL work: each wave owns 64 X-cols
// (4 chains x 16) and a 512-row Y-chunk = 32 x 16-row panels streamed
// global->reg (L2-resident) through NAMED ping-pong buffers yA/yB.
// 16x16x32 MFMA shrinks the live set to ~125 regs (xb 64 + yA/yB 32 + c 16
// + acc 8) -> 4 waves/SIMD resident (vs 2 at the r17/r18 ~180-reg footprint
// -- arch VGPR_Count hides the AGPR accumulators; residency was the 4x gap
// between the ~11us pipe bound and 42us measured).
// Swapped operands (A=Y, B=X): D[row=Y=(l>>4)*4+reg][col=X=l&15]; Y-rowsum
// = sum the 4 regs, accumulate over panels; tail = 2 shfl_xor + 8 atomics.
__global__ __launch_bounds__(256) void sweep_kernel(
    const char* __restrict__ Z1f, const char* __restrict__ Z2f,
    const char* __restrict__ G1f, const char* __restrict__ G2f,
    const char* __restrict__ Af,
    float* __restrict__ S1, float* __restrict__ S2)
{
    int gwid = blockIdx.x * 4 + (threadIdx.x >> 6);   // 0..3071
    int lane = threadIdx.x & 63;

    int job, xblk, ychunk;
    const char *X, *Y;
    if (gwid < 1024) {            // jobs 0/1: 64 xblk x 8 ychunk each
        job = gwid >> 9;
        int rem = gwid & 511;
        xblk = rem >> 3;          // 0..63
        ychunk = rem & 7;         // 0..7 (512 rows each)
        X = job ? G2f : G1f;
        Y = Af;
    } else {                      // jobs 2/3: 64 xblk x 16 ychunk each
        int g2 = gwid - 1024;
        job = 2 + (g2 >> 10);
        int rem = g2 & 1023;
        xblk = rem >> 4;          // 0..63
        int yc = rem & 15;        // 0..15
        X = (job == 2) ? Z1f : Z2f;
        Y = (yc < 8) ? Z1f : Z2f;
        ychunk = yc & 7;
    }

    size_t laneoff = (size_t)lane * 16;

    // X: 4 chains of 16 cols (B operand), in registers for the whole sweep.
    const char* xp = X + (size_t)(xblk * 4) * 4096 + laneoff;
    bf16x8 xb0[4], xb1[4], xb2[4], xb3[4];
    #pragma unroll
    for (int s = 0; s < 4; s++) {
        xb0[s] = *reinterpret_cast<const bf16x8*>(xp + s * 1024);
        xb1[s] = *reinterpret_cast<const bf16x8*>(xp + 4096 + s * 1024);
        xb2[s] = *reinterpret_cast<const bf16x8*>(xp + 8192 + s * 1024);
        xb3[s] = *reinterpret_cast<const bf16x8*>(xp + 12288 + s * 1024);
    }

    // Per-chain accumulators (X-col = xblk*64 + p*16 + (l&15)).
    float a0e = 0.f, a0q = 0.f, a1e = 0.f, a1q = 0.f;
    float a2e = 0.f, a2q = 0.f, a3e = 0.f, a3q = 0.f;

    bf16x8 yA[4], yB[4];
    const char* ybase = Y + (size_t)ychunk * 131072 + laneoff;   // 512 rows

    // panel 0 -> yA
    #pragma unroll
    for (int s = 0; s < 4; s++)
        yA[s] = *reinterpret_cast<const bf16x8*>(ybase + s * 1024);

#define COMPY(BUF)                                                           \
    {                                                                        \
        f32x4 c0 = {0.f,0.f,0.f,0.f}, c1 = {0.f,0.f,0.f,0.f};                \
        f32x4 c2 = {0.f,0.f,0.f,0.f}, c3 = {0.f,0.f,0.f,0.f};                \
        _Pragma("unroll")                                                    \
        for (int s = 0; s < 4; s++) {                                        \
            c0 = __builtin_amdgcn_mfma_f32_16x16x32_bf16(BUF[s], xb0[s], c0, 0, 0, 0); \
            c1 = __builtin_amdgcn_mfma_f32_16x16x32_bf16(BUF[s], xb1[s], c1, 0, 0, 0); \
            c2 = __builtin_amdgcn_mfma_f32_16x16x32_bf16(BUF[s], xb2[s], c2, 0, 0, 0); \
            c3 = __builtin_amdgcn_mfma_f32_16x16x32_bf16(BUF[s], xb3[s], c3, 0, 0, 0); \
        }                                                                    \
        _Pragma("unroll")                                                    \
        for (int q = 0; q < 4; q++) {                                        \
            float e0 = fast_exp2(c0[q]);                                     \
            a0e += e0; a0q = fmaf(e0, e0, a0q);                              \
            float e1 = fast_exp2(c1[q]);                                     \
            a1e += e1; a1q = fmaf(e1, e1, a1q);                              \
            float e2 = fast_exp2(c2[q]);                                     \
            a2e += e2; a2q = fmaf(e2, e2, a2q);                              \
            float e3 = fast_exp2(c3[q]);                                     \
            a3e += e3; a3q = fmaf(e3, e3, a3q);                              \
        }                                                                    \
    }

    #pragma clang loop unroll(disable)
    for (int it = 0; it < 16; it++) {      // 32 panels, ping-pong pairs
        #pragma unroll
        for (int s = 0; s < 4; s++)        // prefetch odd panel -> yB
            yB[s] = *reinterpret_cast<const bf16x8*>(ybase + 4096 + s * 1024);
        COMPY(yA)
        if (it < 15) {
            #pragma unroll
            for (int s = 0; s < 4; s++)    // prefetch next even -> yA
                yA[s] = *reinterpret_cast<const bf16x8*>(ybase + 8192 + s * 1024);
        }
        COMPY(yB)
        ybase += 8192;
    }
#undef COMPY

    // Reduce the 4 lane-groups (disjoint Y-rows, same X-col) and commit.
    #pragma unroll
    for (int k = 16; k <= 32; k <<= 1) {
        a0e += __shfl_xor(a0e, k); a0q += __shfl_xor(a0q, k);
        a1e += __shfl_xor(a1e, k); a1q += __shfl_xor(a1q, k);
        a2e += __shfl_xor(a2e, k); a2q += __shfl_xor(a2q, k);
        a3e += __shfl_xor(a3e, k); a3q += __shfl_xor(a3q, k);
    }
    if (lane < 16) {
        int base = job * BN + xblk * 64 + lane;
        atomicAdd(&S1[base],      a0e); atomicAdd(&S2[base],      a0q);
        atomicAdd(&S1[base + 16], a1e); atomicAdd(&S2[base + 16], a1q);
        atomicAdd(&S1[base + 32], a2e); atomicAdd(&S2[base + 32], a2q);
        atomicAdd(&S1[base + 48], a3e); atomicAdd(&S2[base + 48], a3q);
    }
}

// ---------------- finalize: per-row loss terms -> weighted mean --------------
__global__ __launch_bounds__(256) void finalize_kernel(
    const float* __restrict__ S1, const float* __restrict__ S2,
    const float* __restrict__ d1, const float* __restrict__ d2,
    const float* __restrict__ d3, float* __restrict__ out)
{
    int idx = blockIdx.x * 256 + threadIdx.x;   // 0..16383
    float term = 0.f;
    const float EM2 = 0.13533528323661270f;     // e^-2
    if (idx < 8192) {                           // inter jobs 0/1
        int j = idx >> 12, i = idx & 4095;
        float dv = j ? d2[i] : d1[i];
        float n = 4095.f;
        float pos = __expf(2.f * dv);
        float s1 = S1[j * BN + i] - pos;
        float s2 = S2[j * BN + i] - pos * pos;
        float rw = s2 * n / s1;
        float ng = (-0.1f * n * pos + rw) * (1.f / 0.9f);
        ng = fmaxf(ng, n * EM2);
        term = logf((pos + ng) / pos) * (0.5f / 4096.f);
    } else {                                    // intra rows 0..8191
        int i = idx - 8192;
        int ii = i & 4095;
        int job = 2 + (i >> 12);
        float n = 8190.f;
        const float E2 = 7.3890560989306495f, E4 = 54.598150033144236f;
        float pos = __expf(2.f * d3[ii]);
        float s1 = S1[job * BN + ii] - E2 - pos;
        float s2 = S2[job * BN + ii] - E4 - pos * pos;
        float rw = s2 * n / s1;
        float ng = (-0.1f * n * pos + rw) * (1.f / 0.9f);
        ng = fmaxf(ng, n * EM2);
        term = logf((pos + ng) / pos) * (1.f / 8192.f);
    }

    #pragma unroll
    for (int m = 1; m < 64; m <<= 1) term += __shfl_xor(term, m);
    __shared__ float sm[4];
    int wid = threadIdx.x >> 6;
    if ((threadIdx.x & 63) == 0) sm[wid] = term;
    __syncthreads();
    if (threadIdx.x == 0) atomicAdd(out, sm[0] + sm[1] + sm[2] + sm[3]);
}

extern "C" void kernel_launch(void* const* d_in, const int* in_sizes, int n_in,
                              void* d_out, int out_size, void* d_ws, size_t ws_size,
                              hipStream_t stream)
{
    const float* z1   = (const float*)d_in[0];
    const float* z2   = (const float*)d_in[1];
    // d_in[2] = text_z : unused by the reference
    const float* attr = (const float*)d_in[3];
    const int*   uni  = (const int*)d_in[4];
    float* out = (float*)d_out;

    char* ws = (char*)d_ws;
    size_t matb = (size_t)BN * DD * 2;               // bytes per bf16 matrix
    char* Z1f = ws;
    char* Z2f = Z1f + matb;
    char* G1f = Z2f + matb;
    char* G2f = G1f + matb;
    char* Af  = G2f + matb;
    float* S1 = (float*)(ws + 5 * matb);
    float* S2 = S1 + 4 * BN;
    float* d1 = S2 + 4 * BN;
    float* d2 = d1 + BN;
    float* d3 = d2 + BN;

    prep_kernel<<<256, 256, 0, stream>>>(z1, z2, attr, uni,
                                         Z1f, Z2f, G1f, G2f, Af,
                                         d1, d2, d3, S1, S2, out);
    sweep_kernel<<<768, 256, 0, stream>>>(Z1f, Z2f, G1f, G2f, Af, S1, S2);
    finalize_kernel<<<64, 256, 0, stream>>>(S1, S2, d1, d2, d3, out);
}